// Round 19
// baseline (110.981 us; speedup 1.0000x reference)
//
#include <hip/hip_runtime.h>
#include <hip/hip_bf16.h>
#include <math.h>
#include <string.h>

#define B_SZ  8192
#define KD    256
#define NCLS  32
#define NCHUNK 8          // j-chunks per i-tile row; grid = 64*NCHUNK = 512 blocks
#define JTPC   8          // 128-wide j-tiles per block
#define SCALE_LOG2 3.79828243f   // sqrt(10 * log2(e)): rows scaled so sim' = (sim/T)*log2(e)
#define LN2 0.69314718056f

typedef __attribute__((ext_vector_type(8))) short short8;
typedef __attribute__((ext_vector_type(4))) float f32x4;

static __device__ __forceinline__ unsigned pk2bf(float a, float b) {
    __hip_bfloat162 h = __float22bfloat162_rn(make_float2(a, b));   // v_cvt_pk_bf16_f32
    unsigned u; __builtin_memcpy(&u, &h, 4); return u;
}
static __device__ __forceinline__ unsigned short f2bf1(float f) {
    unsigned u = __float_as_uint(f);
    return (unsigned short)((u + 0x7FFF + ((u >> 16) & 1)) >> 16);   // RNE
}
static __device__ __forceinline__ float fexp2(float x) {   // raw v_exp_f32: D = 2^S0
    float r;
    asm("v_exp_f32 %0, %1" : "=v"(r) : "v"(x));
    return r;
}

// ---------------- kernel 1: normalize+scale rows -> bf16 (log2e folded) ----------------
__global__ void prep_kernel(const float* __restrict__ feat, unsigned short* __restrict__ Fbf) {
    int row  = blockIdx.x * 4 + (threadIdx.x >> 6);
    int lane = threadIdx.x & 63;
    const float4 v = ((const float4*)(feat + (size_t)row * KD))[lane];
    float s = v.x * v.x + v.y * v.y + v.z * v.z + v.w * v.w;
    #pragma unroll
    for (int off = 1; off < 64; off <<= 1) s += __shfl_xor(s, off, 64);
    float rn = rsqrtf(s) * SCALE_LOG2;
    uint2 w;
    w.x = pk2bf(v.x * rn, v.y * rn);
    w.y = pk2bf(v.z * rn, v.w * rn);
    ((uint2*)(Fbf + (size_t)row * KD))[lane] = w;
}

// ---------------- kernel 2: global per-class counts ----------------
__global__ void count_kernel(const int* __restrict__ labels, int* __restrict__ counts) {
    __shared__ int sc[NCLS];
    int t = threadIdx.x;
    if (t < NCLS) sc[t] = 0;
    __syncthreads();
    for (int i = t; i < B_SZ; i += 256) atomicAdd(&sc[labels[i]], 1);
    __syncthreads();
    if (t < NCLS) counts[t] = sc[t];
}

// ---------------- kernel 3: 128x128 bf16 sim GEMM (BK=64), 8 waves (2x4), wave=64x32 ----------------
// 512 blocks x 512 threads; LDS 64KB dbuf -> 2 blocks/CU = 16 waves/CU (4/SIMD) at ~100 VGPR.
__global__ __launch_bounds__(512, 2) void sim_kernel(
    const unsigned short* __restrict__ Fbf, const int* __restrict__ labels,
    unsigned short* __restrict__ pcls, float* __restrict__ ppos)
{
    __shared__ __align__(16) unsigned short sbuf[2][2][128 * 64];  // 64KB: [buf][A/B], BK=64
    __shared__ int   slab[2][128];
    __shared__ float sps[3][128];

    const int bid = blockIdx.x;
    const int swz = (bid & 7) * 64 + (bid >> 3);   // bijective XCD swizzle (512 % 8 == 0)
    const int itile = swz >> 3;                    // swz / NCHUNK
    const int jc    = swz & 7;                     // swz % NCHUNK
    const int i0    = itile * 128;

    const int t    = threadIdx.x;
    const int wave = t >> 6;
    const int lane = t & 63;
    const int wr   = wave >> 2;      // 0..1 -> 64-row half
    const int wc   = wave & 3;       // 0..3 -> 32-col quarter
    const int l15  = lane & 15;
    const int l4   = lane >> 4;

    int labi[4];
    #pragma unroll
    for (int m = 0; m < 4; m++) labi[m] = labels[i0 + wr * 64 + m * 16 + l15];

    const int rT = t >> 3;    // row-within-64 staged per issue (512 threads)
    const int s8 = t & 7;     // physical 16B slot

    auto STAGE = [&](int buf, int j0s, int ks) {
        const int kc = ks * 64;
        #pragma unroll
        for (int a = 0; a < 2; ++a) {
            int r   = a * 64 + rT;
            int sl  = s8 ^ (r & 7);          // logical k-slot (involution)
            int col = kc + sl * 8;
            const unsigned short* gA = Fbf + (size_t)(i0 + r) * KD + col;
            char* lA = (char*)&sbuf[buf][0][0] + a * 8192 + wave * 1024;
            __builtin_amdgcn_global_load_lds(
                (const __attribute__((address_space(1))) void*)gA,
                (__attribute__((address_space(3))) void*)lA, 16, 0, 0);
            const unsigned short* gB = Fbf + (size_t)(j0s + r) * KD + col;
            char* lB = (char*)&sbuf[buf][1][0] + a * 8192 + wave * 1024;
            __builtin_amdgcn_global_load_lds(
                (const __attribute__((address_space(1))) void*)gB,
                (__attribute__((address_space(3))) void*)lB, 16, 0, 0);
        }
    };

    // persistent accumulators across the block's 8 j-tiles
    f32x4 acc_cs[4][2];
    float psum[4] = {0.f, 0.f, 0.f, 0.f};
    #pragma unroll
    for (int m = 0; m < 4; m++)
        #pragma unroll
        for (int cb = 0; cb < 2; cb++)
            acc_cs[m][cb] = (f32x4){0.f, 0.f, 0.f, 0.f};

    const int jt_beg = jc * JTPC, jt_end = (jc + 1) * JTPC;
    if (t < 128) slab[0][t] = labels[jt_beg * 128 + t];
    STAGE(0, jt_beg * 128, 0);   // prologue: first tile's k=0

    #pragma unroll 1
    for (int jt = jt_beg; jt < jt_end; ++jt) {
        const int j0 = jt * 128;
        const int cur = jt & 1;

        __syncthreads();   // drains prefetch (vm+lgkm); slab[cur] visible; sE reads done

        f32x4 acc[4][2];
        #pragma unroll
        for (int m = 0; m < 4; m++)
            #pragma unroll
            for (int n = 0; n < 2; n++)
                acc[m][n] = (f32x4){0.f, 0.f, 0.f, 0.f};

        // ---- 2-phase pipelined K-loop: 4 steps of BK=64 ----
        #pragma unroll 1
        for (int ks = 0; ks < 4; ++ks) {
            if (ks < 3) STAGE((ks + 1) & 1, j0, ks + 1);
            const unsigned short* pA = &sbuf[ks & 1][0][0];
            const unsigned short* pB = &sbuf[ks & 1][1][0];
            short8 bf4[2][2];
            #pragma unroll
            for (int n = 0; n < 2; ++n) {
                int r = wc * 32 + n * 16 + l15;
                #pragma unroll
                for (int kk = 0; kk < 2; ++kk)
                    bf4[n][kk] = *(const short8*)&pB[r * 64 + (((kk * 4 + l4) ^ (r & 7)) * 8)];
            }
            __builtin_amdgcn_s_setprio(1);
            #pragma unroll
            for (int m = 0; m < 4; ++m) {
                int r = wr * 64 + m * 16 + l15;
                short8 a0 = *(const short8*)&pA[r * 64 + ((l4 ^ (r & 7)) * 8)];
                short8 a1 = *(const short8*)&pA[r * 64 + (((4 + l4) ^ (r & 7)) * 8)];
                #pragma unroll
                for (int n = 0; n < 2; ++n) {   // swapped operands: q indexes j
                    acc[m][n] = __builtin_amdgcn_mfma_f32_16x16x32_bf16(bf4[n][0], a0, acc[m][n], 0, 0, 0);
                    acc[m][n] = __builtin_amdgcn_mfma_f32_16x16x32_bf16(bf4[n][1], a1, acc[m][n], 0, 0, 0);
                }
            }
            __builtin_amdgcn_s_setprio(0);
            __syncthreads();   // drains next stage; swaps buffers
        }

        // ---- prefetch next tile's k=0 into buf0 (dead); flies under epilogue ----
        if (jt + 1 < jt_end) {
            STAGE(0, (jt + 1) * 128, 0);
            if (t < 128) slab[cur ^ 1][t] = labels[(jt + 1) * 128 + t];
        }

        // ---- fused epilogue: psum + E=2^sim' + cvt_pk -> wave-private sE [64 i][32 j] bf16 (4KB) ----
        char* sEw = (char*)&sbuf[1][0][0] + wave * 4096;   // buf1 dead after K-loop barrier

        int4 lj4[2];
        #pragma unroll
        for (int n = 0; n < 2; n++)
            lj4[n] = *(const int4*)&slab[cur][wc * 32 + n * 16 + l4 * 4];

        if (j0 != i0) {
            #pragma unroll
            for (int m = 0; m < 4; m++) {
                const int row = m * 16 + l15;
                #pragma unroll
                for (int n = 0; n < 2; n++) {
                    const int* ljp = (const int*)&lj4[n];
                    float e[4];
                    #pragma unroll
                    for (int q = 0; q < 4; q++) {
                        float sp = acc[m][n][q];                    // log2-scaled sim
                        psum[m] += (ljp[q] == labi[m]) ? sp : 0.0f;
                        e[q] = fexp2(sp);
                    }
                    uint2 w; w.x = pk2bf(e[0], e[1]); w.y = pk2bf(e[2], e[3]);
                    const int bc = (n * 32 + l4 * 8) ^ ((row & 3) << 4);
                    *(uint2*)(sEw + row * 64 + bc) = w;
                }
            }
        } else {   // diagonal tile: exclude self
            #pragma unroll
            for (int m = 0; m < 4; m++) {
                const int row = m * 16 + l15;
                const int ig = i0 + wr * 64 + row;
                #pragma unroll
                for (int n = 0; n < 2; n++) {
                    const int jb = wc * 32 + n * 16 + l4 * 4;
                    const int* ljp = (const int*)&lj4[n];
                    float e[4];
                    #pragma unroll
                    for (int q = 0; q < 4; q++) {
                        const int jg = j0 + jb + q;
                        float sp = acc[m][n][q];
                        bool self = (ig == jg);
                        psum[m] += (!self && ljp[q] == labi[m]) ? sp : 0.0f;
                        e[q] = self ? 0.0f : fexp2(sp);
                    }
                    uint2 w; w.x = pk2bf(e[0], e[1]); w.y = pk2bf(e[2], e[3]);
                    const int bc = (n * 32 + l4 * 8) ^ ((row & 3) << 4);
                    *(uint2*)(sEw + row * 64 + bc) = w;
                }
            }
        }

        // one-hot B-fragments over this wave's 32 j-cols (single K=32 slice)
        short8 hf[2];
        {
            const int jb = wc * 32 + l4 * 8;
            int4 lv0 = *(const int4*)&slab[cur][jb];
            int4 lv1 = *(const int4*)&slab[cur][jb + 4];
            int lv[8] = {lv0.x, lv0.y, lv0.z, lv0.w, lv1.x, lv1.y, lv1.z, lv1.w};
            #pragma unroll
            for (int cb = 0; cb < 2; cb++) {
                short8 h;
                #pragma unroll
                for (int e = 0; e < 8; e++)
                    h[e] = (lv[e] == cb * 16 + l15) ? (short)0x3F80 : (short)0;
                hf[cb] = h;
            }
        }

        // CS MFMA from sEw (accumulate into persistent acc_cs): 8 MFMA
        #pragma unroll
        for (int m = 0; m < 4; m++) {
            const int row = m * 16 + l15;
            const int bc = (l4 * 16) ^ ((row & 3) << 4);
            short8 ef = *(const short8*)(sEw + row * 64 + bc);
            #pragma unroll
            for (int cb = 0; cb < 2; cb++)
                acc_cs[m][cb] = __builtin_amdgcn_mfma_f32_16x16x32_bf16(
                    ef, hf[cb], acc_cs[m][cb], 0, 0, 0);
        }
        // no barrier here: loop-top __syncthreads() protects buffers before reuse
    }

    // ---- block end: cross-wave (wc 0..3) reduce of CS + psum, write partials (pcls bf16) ----
    __syncthreads();
    float* scr = (float*)&sbuf[0][0][0];   // [3][128][33] f32 = 50.8KB over dead dbuf
    float pv[4];
    #pragma unroll
    for (int m = 0; m < 4; m++) {
        float v = psum[m];
        v += __shfl_xor(v, 16, 64);
        v += __shfl_xor(v, 32, 64);
        pv[m] = v;
    }
    if (wc > 0) {
        const int k = wc - 1;
        #pragma unroll
        for (int m = 0; m < 4; m++) {
            #pragma unroll
            for (int cb = 0; cb < 2; cb++)
                #pragma unroll
                for (int q = 0; q < 4; q++)
                    scr[(size_t)k * 4224 + (wr * 64 + m * 16 + l4 * 4 + q) * 33 + cb * 16 + l15] =
                        acc_cs[m][cb][q];
            if (l4 == 0) sps[k][wr * 64 + m * 16 + l15] = pv[m];
        }
    }
    __syncthreads();
    if (wc == 0) {
        const size_t slot = (size_t)itile * NCHUNK + jc;
        unsigned short* pc = pcls + slot * 128 * NCLS;
        #pragma unroll
        for (int m = 0; m < 4; m++) {
            #pragma unroll
            for (int cb = 0; cb < 2; cb++)
                #pragma unroll
                for (int q = 0; q < 4; q++) {
                    const int r = wr * 64 + m * 16 + l4 * 4 + q;
                    const int c = cb * 16 + l15;
                    float v = acc_cs[m][cb][q];
                    #pragma unroll
                    for (int k = 0; k < 3; k++) v += scr[(size_t)k * 4224 + r * 33 + c];
                    pc[r * NCLS + c] = f2bf1(v);
                }
            if (l4 == 0) {
                const int r = wr * 64 + m * 16 + l15;
                float v = pv[m] + sps[0][r] + sps[1][r] + sps[2][r];
                ppos[slot * 128 + r] = v * LN2;   // back to 1/T units
            }
        }
    }
}

// ---------------- kernel 4: per-anchor loss (8 lanes per anchor) ----------------
__global__ void reduce_kernel(const unsigned short* __restrict__ pcls, const float* __restrict__ ppos,
                              const int* __restrict__ counts, const int* __restrict__ labels,
                              float* __restrict__ loss_i, float* __restrict__ validf) {
    int tid = blockIdx.x * blockDim.x + threadIdx.x;
    int i  = tid >> 3;
    int cq = tid & 7;
    if (i >= B_SZ) return;
    int itile = i >> 7, ilocal = i & 127;

    f32x4 cs = (f32x4){0.f, 0.f, 0.f, 0.f};
    for (int ch = 0; ch < NCHUNK; ch++) {
        const unsigned short* p = pcls + ((size_t)(itile * NCHUNK + ch) * 128 + ilocal) * NCLS + cq * 4;
        ushort4 v = *(const ushort4*)p;
        const unsigned short* vp = (const unsigned short*)&v;
        #pragma unroll
        for (int e = 0; e < 4; e++)
            cs[e] += __uint_as_float((unsigned)vp[e] << 16);
    }
    int labi = labels[i];
    float dpart = 0.0f;
    #pragma unroll
    for (int e = 0; e < 4; e++) {
        int c = cq * 4 + e;
        int cnt = counts[c] - (c == labi ? 1 : 0);
        if (cnt > 0) dpart += cs[e] / (float)cnt;
    }
    #pragma unroll
    for (int off = 1; off < 8; off <<= 1) dpart += __shfl_xor(dpart, off, 64);

    if (cq == 0) {
        float psum = 0.0f;
        for (int ch = 0; ch < NCHUNK; ch++)
            psum += ppos[(size_t)(itile * NCHUNK + ch) * 128 + ilocal];
        int P = counts[labi] - 1;
        bool valid = P > 0;
        float li = 0.0f;
        if (valid) li = logf(fmaxf(dpart, 1e-30f)) - psum / (float)max(P, 1);
        loss_i[i] = li;
        validf[i] = valid ? 1.0f : 0.0f;
    }
}

// ---------------- kernel 5: deterministic final reduction ----------------
__global__ void final_kernel(const float* __restrict__ loss_i, const float* __restrict__ validf,
                             float* __restrict__ out) {
    __shared__ float ssum[256];
    __shared__ float scnt[256];
    int t = threadIdx.x;
    float s = 0.0f, c = 0.0f;
    for (int i = t; i < B_SZ; i += 256) { s += loss_i[i]; c += validf[i]; }
    ssum[t] = s; scnt[t] = c;
    __syncthreads();
    #pragma unroll
    for (int off = 128; off > 0; off >>= 1) {
        if (t < off) { ssum[t] += ssum[t + off]; scnt[t] += scnt[t + off]; }
        __syncthreads();
    }
    if (t == 0) out[0] = (scnt[0] > 0.0f) ? ssum[0] / scnt[0] : 0.0f;
}

// ---------------- launch ----------------
extern "C" void kernel_launch(void* const* d_in, const int* in_sizes, int n_in,
                              void* d_out, int out_size, void* d_ws, size_t ws_size,
                              hipStream_t stream) {
    const float* feat   = (const float*)d_in[0];
    const int*   labels = (const int*)d_in[1];
    float*       out    = (float*)d_out;

    char* ws = (char*)d_ws;
    size_t off = 0;
    auto alloc = [&](size_t bytes) -> void* {
        void* p = ws + off;
        off = (off + bytes + 255) & ~(size_t)255;
        return p;
    };

    unsigned short* Fbf = (unsigned short*)alloc((size_t)B_SZ * KD * 2);      // 4.2MB
    int*   counts = (int*)alloc((size_t)NCLS * 4);
    float* loss_i = (float*)alloc((size_t)B_SZ * 4);
    float* validf = (float*)alloc((size_t)B_SZ * 4);
    float* ppos   = (float*)alloc((size_t)512 * 128 * 4);                     // 256KB
    unsigned short* pcls = (unsigned short*)alloc((size_t)512 * 128 * NCLS * 2);   // 4.2MB bf16

    prep_kernel<<<B_SZ / 4, 256, 0, stream>>>(feat, Fbf);
    count_kernel<<<1, 256, 0, stream>>>(labels, counts);
    sim_kernel<<<512, 512, 0, stream>>>(Fbf, labels, pcls, ppos);
    reduce_kernel<<<B_SZ * 8 / 256, 256, 0, stream>>>(pcls, ppos, counts, labels, loss_i, validf);
    final_kernel<<<1, 256, 0, stream>>>(loss_i, validf, out);
}

// Round 20
// 83.286 us; speedup vs baseline: 1.3325x; 1.3325x over previous
//
#include <hip/hip_runtime.h>
#include <hip/hip_bf16.h>
#include <math.h>
#include <string.h>

#define B_SZ  8192
#define KD    256
#define NCLS  32
#define NCHUNK 8          // j-chunks per i-tile row; grid = 64*NCHUNK = 512 blocks
#define JTPC   8          // 128-wide j-tiles per block
#define SCALE_LOG2 3.79828243f   // sqrt(10 * log2(e)): rows scaled so sim' = (sim/T)*log2(e)
#define LN2 0.69314718056f

typedef __attribute__((ext_vector_type(8))) short short8;
typedef __attribute__((ext_vector_type(4))) float f32x4;

static __device__ __forceinline__ unsigned pk2bf(float a, float b) {
    __hip_bfloat162 h = __float22bfloat162_rn(make_float2(a, b));   // v_cvt_pk_bf16_f32
    unsigned u; __builtin_memcpy(&u, &h, 4); return u;
}
static __device__ __forceinline__ float fexp2(float x) {   // raw v_exp_f32: D = 2^S0
    float r;
    asm("v_exp_f32 %0, %1" : "=v"(r) : "v"(x));
    return r;
}

// ---------------- kernel 1: normalize+scale rows -> bf16 (log2e folded) ----------------
__global__ void prep_kernel(const float* __restrict__ feat, unsigned short* __restrict__ Fbf) {
    int row  = blockIdx.x * 4 + (threadIdx.x >> 6);
    int lane = threadIdx.x & 63;
    const float4 v = ((const float4*)(feat + (size_t)row * KD))[lane];
    float s = v.x * v.x + v.y * v.y + v.z * v.z + v.w * v.w;
    #pragma unroll
    for (int off = 1; off < 64; off <<= 1) s += __shfl_xor(s, off, 64);
    float rn = rsqrtf(s) * SCALE_LOG2;
    uint2 w;
    w.x = pk2bf(v.x * rn, v.y * rn);
    w.y = pk2bf(v.z * rn, v.w * rn);
    ((uint2*)(Fbf + (size_t)row * KD))[lane] = w;
}

// ---------------- kernel 2: global per-class counts ----------------
__global__ void count_kernel(const int* __restrict__ labels, int* __restrict__ counts) {
    __shared__ int sc[NCLS];
    int t = threadIdx.x;
    if (t < NCLS) sc[t] = 0;
    __syncthreads();
    for (int i = t; i < B_SZ; i += 256) atomicAdd(&sc[labels[i]], 1);
    __syncthreads();
    if (t < NCLS) counts[t] = sc[t];
}

// ---------------- kernel 3: 128x128 bf16 sim GEMM (BK=64) + fused epilogue + MFMA class reduce ----------------
// 512 blocks (2/CU), 256 threads = 4 waves 2x2; wave owns 64x64 of C.
__global__ __launch_bounds__(256, 2) void sim_kernel(
    const unsigned short* __restrict__ Fbf, const int* __restrict__ labels,
    float* __restrict__ pcls, float* __restrict__ ppos)
{
    __shared__ __align__(16) unsigned short sbuf[2][2][128 * 64];  // 64KB: [buf][A/B], BK=64
    __shared__ int   slab[2][128];
    __shared__ float sps[128];

    const int bid = blockIdx.x;
    const int swz = (bid & 7) * 64 + (bid >> 3);   // bijective XCD swizzle (512 % 8 == 0)
    const int itile = swz >> 3;                    // swz / NCHUNK
    const int jc    = swz & 7;                     // swz % NCHUNK
    const int i0    = itile * 128;

    const int t    = threadIdx.x;
    const int wave = t >> 6;
    const int lane = t & 63;
    const int wr   = wave >> 1;      // 0..1 -> 64-row half
    const int wc   = wave & 1;       // 0..1 -> 64-col half
    const int l15  = lane & 15;
    const int l4   = lane >> 4;

    int labi[4];
    #pragma unroll
    for (int m = 0; m < 4; m++) labi[m] = labels[i0 + wr * 64 + m * 16 + l15];

    const int rT = t >> 3;    // row-within-32 staged per quarter
    const int s8 = t & 7;     // physical 16B slot

    auto STAGE = [&](int buf, int j0s, int ks) {
        const int kc = ks * 64;
        #pragma unroll
        for (int a = 0; a < 4; ++a) {
            int r   = a * 32 + rT;
            int sl  = s8 ^ (r & 7);          // logical k-slot (involution)
            int col = kc + sl * 8;
            const unsigned short* gA = Fbf + (size_t)(i0 + r) * KD + col;
            char* lA = (char*)&sbuf[buf][0][0] + a * 4096 + wave * 1024;
            __builtin_amdgcn_global_load_lds(
                (const __attribute__((address_space(1))) void*)gA,
                (__attribute__((address_space(3))) void*)lA, 16, 0, 0);
            const unsigned short* gB = Fbf + (size_t)(j0s + r) * KD + col;
            char* lB = (char*)&sbuf[buf][1][0] + a * 4096 + wave * 1024;
            __builtin_amdgcn_global_load_lds(
                (const __attribute__((address_space(1))) void*)gB,
                (__attribute__((address_space(3))) void*)lB, 16, 0, 0);
        }
    };

    // persistent accumulators across the block's 8 j-tiles
    f32x4 acc_cs[4][2];
    float psum[4] = {0.f, 0.f, 0.f, 0.f};
    #pragma unroll
    for (int m = 0; m < 4; m++)
        #pragma unroll
        for (int cb = 0; cb < 2; cb++)
            acc_cs[m][cb] = (f32x4){0.f, 0.f, 0.f, 0.f};

    const int jt_beg = jc * JTPC, jt_end = (jc + 1) * JTPC;
    if (t < 128) slab[0][t] = labels[jt_beg * 128 + t];
    STAGE(0, jt_beg * 128, 0);   // prologue: first tile's k=0

    #pragma unroll 1
    for (int jt = jt_beg; jt < jt_end; ++jt) {
        const int j0 = jt * 128;
        const int cur = jt & 1;

        __syncthreads();   // drains prefetch (vm+lgkm); slab[cur] visible; sE reads done

        f32x4 acc[4][4];
        #pragma unroll
        for (int m = 0; m < 4; m++)
            #pragma unroll
            for (int n = 0; n < 4; n++)
                acc[m][n] = (f32x4){0.f, 0.f, 0.f, 0.f};

        // ---- 2-phase pipelined K-loop: 4 steps of BK=64 ----
        #pragma unroll 1
        for (int ks = 0; ks < 4; ++ks) {
            if (ks < 3) STAGE((ks + 1) & 1, j0, ks + 1);
            const unsigned short* pA = &sbuf[ks & 1][0][0];
            const unsigned short* pB = &sbuf[ks & 1][1][0];
            short8 bf4[4][2];
            #pragma unroll
            for (int n = 0; n < 4; ++n) {
                int r = wc * 64 + n * 16 + l15;
                #pragma unroll
                for (int kk = 0; kk < 2; ++kk)
                    bf4[n][kk] = *(const short8*)&pB[r * 64 + (((kk * 4 + l4) ^ (r & 7)) * 8)];
            }
            __builtin_amdgcn_s_setprio(1);
            #pragma unroll
            for (int m = 0; m < 4; ++m) {
                int r = wr * 64 + m * 16 + l15;
                short8 a0 = *(const short8*)&pA[r * 64 + ((l4 ^ (r & 7)) * 8)];
                short8 a1 = *(const short8*)&pA[r * 64 + (((4 + l4) ^ (r & 7)) * 8)];
                #pragma unroll
                for (int n = 0; n < 4; ++n) {   // swapped operands: q indexes j
                    acc[m][n] = __builtin_amdgcn_mfma_f32_16x16x32_bf16(bf4[n][0], a0, acc[m][n], 0, 0, 0);
                    acc[m][n] = __builtin_amdgcn_mfma_f32_16x16x32_bf16(bf4[n][1], a1, acc[m][n], 0, 0, 0);
                }
            }
            __builtin_amdgcn_s_setprio(0);
            __syncthreads();   // drains next stage; swaps buffers
        }

        // ---- prefetch next tile's k=0 into buf0 (dead); flies under epilogue ----
        if (jt + 1 < jt_end) STAGE(0, (jt + 1) * 128, 0);
        // load next tile's labels (double-buffered slab)
        if (jt + 1 < jt_end && t < 128) slab[cur ^ 1][t] = labels[(jt + 1) * 128 + t];

        // ---- fused epilogue: psum + E=2^sim' + cvt_pk pack -> wave-private sE [64][64] bf16 ----
        char* sEw = (char*)&sbuf[1][0][0] + wave * 8192;   // buf1 dead after K-loop barrier

        int4 lj4[4];                                       // hoisted: this wave-lane's j labels
        #pragma unroll
        for (int n = 0; n < 4; n++)
            lj4[n] = *(const int4*)&slab[cur][wc * 64 + n * 16 + l4 * 4];

        if (j0 != i0) {
            #pragma unroll
            for (int m = 0; m < 4; m++) {
                const int row = m * 16 + l15;
                #pragma unroll
                for (int n = 0; n < 4; n++) {
                    const int* ljp = (const int*)&lj4[n];
                    float e[4];
                    #pragma unroll
                    for (int q = 0; q < 4; q++) {
                        float sp = acc[m][n][q];                    // log2-scaled sim
                        psum[m] += (ljp[q] == labi[m]) ? sp : 0.0f;
                        e[q] = fexp2(sp);
                    }
                    uint2 w; w.x = pk2bf(e[0], e[1]); w.y = pk2bf(e[2], e[3]);
                    const int bc = (n * 32 + l4 * 8) ^ ((row & 7) << 4);
                    *(uint2*)(sEw + row * 128 + bc) = w;
                }
            }
        } else {   // diagonal tile: exclude self
            #pragma unroll
            for (int m = 0; m < 4; m++) {
                const int row = m * 16 + l15;
                const int ig = i0 + wr * 64 + row;
                #pragma unroll
                for (int n = 0; n < 4; n++) {
                    const int jb = wc * 64 + n * 16 + l4 * 4;
                    const int* ljp = (const int*)&lj4[n];
                    float e[4];
                    #pragma unroll
                    for (int q = 0; q < 4; q++) {
                        const int jg = j0 + jb + q;
                        float sp = acc[m][n][q];
                        bool self = (ig == jg);
                        psum[m] += (!self && ljp[q] == labi[m]) ? sp : 0.0f;
                        e[q] = self ? 0.0f : fexp2(sp);
                    }
                    uint2 w; w.x = pk2bf(e[0], e[1]); w.y = pk2bf(e[2], e[3]);
                    const int bc = (n * 32 + l4 * 8) ^ ((row & 7) << 4);
                    *(uint2*)(sEw + row * 128 + bc) = w;
                }
            }
        }

        // one-hot B-fragments over this wave's 64 j-cols (2 K=32 slices)
        short8 hf[2][2];
        #pragma unroll
        for (int kk = 0; kk < 2; kk++) {
            const int jb = wc * 64 + kk * 32 + l4 * 8;
            int4 lv0 = *(const int4*)&slab[cur][jb];
            int4 lv1 = *(const int4*)&slab[cur][jb + 4];
            int lv[8] = {lv0.x, lv0.y, lv0.z, lv0.w, lv1.x, lv1.y, lv1.z, lv1.w};
            #pragma unroll
            for (int cb = 0; cb < 2; cb++) {
                short8 h;
                #pragma unroll
                for (int e = 0; e < 8; e++)
                    h[e] = (lv[e] == cb * 16 + l15) ? (short)0x3F80 : (short)0;
                hf[kk][cb] = h;
            }
        }

        // CS MFMA from sEw (accumulate into persistent acc_cs)
        #pragma unroll
        for (int kk = 0; kk < 2; kk++) {
            #pragma unroll
            for (int m = 0; m < 4; m++) {
                const int row = m * 16 + l15;
                const int bc = (kk * 64 + l4 * 16) ^ ((row & 7) << 4);
                short8 ef = *(const short8*)(sEw + row * 128 + bc);
                #pragma unroll
                for (int cb = 0; cb < 2; cb++)
                    acc_cs[m][cb] = __builtin_amdgcn_mfma_f32_16x16x32_bf16(
                        ef, hf[kk][cb], acc_cs[m][cb], 0, 0, 0);
            }
        }
        // no barrier here: loop-top __syncthreads() protects buffers before reuse
    }

    // ---- block end: cross-wave (wc) reduce of CS + psum, write partials ----
    __syncthreads();
    float* scr = (float*)&sbuf[0][0][0];   // [128][33] f32 over dead dbuf
    float pv[4];
    #pragma unroll
    for (int m = 0; m < 4; m++) {
        float v = psum[m];
        v += __shfl_xor(v, 16, 64);
        v += __shfl_xor(v, 32, 64);
        pv[m] = v;
    }
    if (wc == 1) {
        #pragma unroll
        for (int m = 0; m < 4; m++) {
            #pragma unroll
            for (int cb = 0; cb < 2; cb++)
                #pragma unroll
                for (int q = 0; q < 4; q++)
                    scr[(wr * 64 + m * 16 + l4 * 4 + q) * 33 + cb * 16 + l15] =
                        acc_cs[m][cb][q];
            if (l4 == 0) sps[wr * 64 + m * 16 + l15] = pv[m];
        }
    }
    __syncthreads();
    if (wc == 0) {
        const size_t slot = (size_t)itile * NCHUNK + jc;
        float* pc = pcls + slot * 128 * NCLS;
        #pragma unroll
        for (int m = 0; m < 4; m++) {
            #pragma unroll
            for (int cb = 0; cb < 2; cb++)
                #pragma unroll
                for (int q = 0; q < 4; q++) {
                    const int r = wr * 64 + m * 16 + l4 * 4 + q;
                    const int c = cb * 16 + l15;
                    pc[r * NCLS + c] = acc_cs[m][cb][q] + scr[r * 33 + c];
                }
            if (l4 == 0)
                ppos[slot * 128 + wr * 64 + m * 16 + l15] =
                    (pv[m] + sps[wr * 64 + m * 16 + l15]) * LN2;   // back to 1/T units
        }
    }
}

// ---------------- kernel 4: per-anchor loss (8 lanes per anchor) ----------------
__global__ void reduce_kernel(const float* __restrict__ pcls, const float* __restrict__ ppos,
                              const int* __restrict__ counts, const int* __restrict__ labels,
                              float* __restrict__ loss_i, float* __restrict__ validf) {
    int tid = blockIdx.x * blockDim.x + threadIdx.x;
    int i  = tid >> 3;
    int cq = tid & 7;
    if (i >= B_SZ) return;
    int itile = i >> 7, ilocal = i & 127;

    f32x4 cs = (f32x4){0.f, 0.f, 0.f, 0.f};
    for (int ch = 0; ch < NCHUNK; ch++) {
        const float* p = pcls + ((size_t)(itile * NCHUNK + ch) * 128 + ilocal) * NCLS + cq * 4;
        f32x4 v = *(const f32x4*)p;
        cs = cs + v;
    }
    int labi = labels[i];
    float dpart = 0.0f;
    #pragma unroll
    for (int e = 0; e < 4; e++) {
        int c = cq * 4 + e;
        int cnt = counts[c] - (c == labi ? 1 : 0);
        if (cnt > 0) dpart += cs[e] / (float)cnt;
    }
    #pragma unroll
    for (int off = 1; off < 8; off <<= 1) dpart += __shfl_xor(dpart, off, 64);

    if (cq == 0) {
        float psum = 0.0f;
        for (int ch = 0; ch < NCHUNK; ch++)
            psum += ppos[(size_t)(itile * NCHUNK + ch) * 128 + ilocal];
        int P = counts[labi] - 1;
        bool valid = P > 0;
        float li = 0.0f;
        if (valid) li = logf(fmaxf(dpart, 1e-30f)) - psum / (float)max(P, 1);
        loss_i[i] = li;
        validf[i] = valid ? 1.0f : 0.0f;
    }
}

// ---------------- kernel 5: deterministic final reduction ----------------
__global__ void final_kernel(const float* __restrict__ loss_i, const float* __restrict__ validf,
                             float* __restrict__ out) {
    __shared__ float ssum[256];
    __shared__ float scnt[256];
    int t = threadIdx.x;
    float s = 0.0f, c = 0.0f;
    for (int i = t; i < B_SZ; i += 256) { s += loss_i[i]; c += validf[i]; }
    ssum[t] = s; scnt[t] = c;
    __syncthreads();
    #pragma unroll
    for (int off = 128; off > 0; off >>= 1) {
        if (t < off) { ssum[t] += ssum[t + off]; scnt[t] += scnt[t + off]; }
        __syncthreads();
    }
    if (t == 0) out[0] = (scnt[0] > 0.0f) ? ssum[0] / scnt[0] : 0.0f;
}

// ---------------- launch ----------------
extern "C" void kernel_launch(void* const* d_in, const int* in_sizes, int n_in,
                              void* d_out, int out_size, void* d_ws, size_t ws_size,
                              hipStream_t stream) {
    const float* feat   = (const float*)d_in[0];
    const int*   labels = (const int*)d_in[1];
    float*       out    = (float*)d_out;

    char* ws = (char*)d_ws;
    size_t off = 0;
    auto alloc = [&](size_t bytes) -> void* {
        void* p = ws + off;
        off = (off + bytes + 255) & ~(size_t)255;
        return p;
    };

    unsigned short* Fbf = (unsigned short*)alloc((size_t)B_SZ * KD * 2);      // 4.2MB
    int*   counts = (int*)alloc((size_t)NCLS * 4);
    float* loss_i = (float*)alloc((size_t)B_SZ * 4);
    float* validf = (float*)alloc((size_t)B_SZ * 4);
    float* ppos   = (float*)alloc((size_t)512 * 128 * 4);                     // 256KB
    float* pcls   = (float*)alloc((size_t)512 * 128 * NCLS * 4);              // 8.4MB

    prep_kernel<<<B_SZ / 4, 256, 0, stream>>>(feat, Fbf);
    count_kernel<<<1, 256, 0, stream>>>(labels, counts);
    sim_kernel<<<512, 256, 0, stream>>>(Fbf, labels, pcls, ppos);
    reduce_kernel<<<B_SZ * 8 / 256, 256, 0, stream>>>(pcls, ppos, counts, labels, loss_i, validf);
    final_kernel<<<1, 256, 0, stream>>>(loss_i, validf, out);
}

// Round 21
// 80.342 us; speedup vs baseline: 1.3814x; 1.0366x over previous
//
#include <hip/hip_runtime.h>
#include <hip/hip_bf16.h>
#include <math.h>
#include <string.h>

#define B_SZ  8192
#define KD    256
#define NCLS  32
#define NCHUNK 8          // j-chunks per i-tile row; grid = 64*NCHUNK = 512 blocks
#define JTPC   8          // 128-wide j-tiles per block
#define SCALE_LOG2 3.79828243f   // sqrt(10 * log2(e)): rows scaled so sim' = (sim/T)*log2(e)
#define LN2 0.69314718056f
#define ACC_SCALE 2048.0f        // fixed-point scale for deterministic loss accumulation

typedef __attribute__((ext_vector_type(8))) short short8;
typedef __attribute__((ext_vector_type(4))) float f32x4;

static __device__ __forceinline__ unsigned pk2bf(float a, float b) {
    __hip_bfloat162 h = __float22bfloat162_rn(make_float2(a, b));   // v_cvt_pk_bf16_f32
    unsigned u; __builtin_memcpy(&u, &h, 4); return u;
}
static __device__ __forceinline__ float fexp2(float x) {   // raw v_exp_f32: D = 2^S0
    float r;
    asm("v_exp_f32 %0, %1" : "=v"(r) : "v"(x));
    return r;
}

// ---------------- kernel 1: normalize+scale rows -> bf16 (log2e folded) + fused label counts ----------------
__global__ void prep_kernel(const float* __restrict__ feat, unsigned short* __restrict__ Fbf,
                            const int* __restrict__ labels, int* __restrict__ counts) {
    __shared__ int sc[NCLS];
    const int blk = blockIdx.x;
    const int t   = threadIdx.x;
    const bool docnt = (blk < 32);   // 32 blocks x 256 labels = 8192
    if (docnt) {
        if (t < NCLS) sc[t] = 0;
        __syncthreads();
        atomicAdd(&sc[labels[blk * 256 + t]], 1);
    }

    int row  = blk * 4 + (t >> 6);
    int lane = t & 63;
    const float4 v = ((const float4*)(feat + (size_t)row * KD))[lane];
    float s = v.x * v.x + v.y * v.y + v.z * v.z + v.w * v.w;
    #pragma unroll
    for (int off = 1; off < 64; off <<= 1) s += __shfl_xor(s, off, 64);
    float rn = rsqrtf(s) * SCALE_LOG2;
    uint2 w;
    w.x = pk2bf(v.x * rn, v.y * rn);
    w.y = pk2bf(v.z * rn, v.w * rn);
    ((uint2*)(Fbf + (size_t)row * KD))[lane] = w;

    if (docnt) {
        __syncthreads();
        if (t < NCLS) atomicAdd(&counts[t], sc[t]);
    }
}

// ---------------- kernel 2: 128x128 bf16 sim GEMM (BK=64) + fused epilogue + MFMA class reduce ----------------
// 512 blocks (2/CU), 256 threads = 4 waves 2x2; wave owns 64x64 of C.  [verified R17/R20 form]
__global__ __launch_bounds__(256, 2) void sim_kernel(
    const unsigned short* __restrict__ Fbf, const int* __restrict__ labels,
    float* __restrict__ pcls, float* __restrict__ ppos)
{
    __shared__ __align__(16) unsigned short sbuf[2][2][128 * 64];  // 64KB: [buf][A/B], BK=64
    __shared__ int   slab[2][128];
    __shared__ float sps[128];

    const int bid = blockIdx.x;
    const int swz = (bid & 7) * 64 + (bid >> 3);   // bijective XCD swizzle (512 % 8 == 0)
    const int itile = swz >> 3;                    // swz / NCHUNK
    const int jc    = swz & 7;                     // swz % NCHUNK
    const int i0    = itile * 128;

    const int t    = threadIdx.x;
    const int wave = t >> 6;
    const int lane = t & 63;
    const int wr   = wave >> 1;      // 0..1 -> 64-row half
    const int wc   = wave & 1;       // 0..1 -> 64-col half
    const int l15  = lane & 15;
    const int l4   = lane >> 4;

    int labi[4];
    #pragma unroll
    for (int m = 0; m < 4; m++) labi[m] = labels[i0 + wr * 64 + m * 16 + l15];

    const int rT = t >> 3;    // row-within-32 staged per quarter
    const int s8 = t & 7;     // physical 16B slot

    auto STAGE = [&](int buf, int j0s, int ks) {
        const int kc = ks * 64;
        #pragma unroll
        for (int a = 0; a < 4; ++a) {
            int r   = a * 32 + rT;
            int sl  = s8 ^ (r & 7);          // logical k-slot (involution)
            int col = kc + sl * 8;
            const unsigned short* gA = Fbf + (size_t)(i0 + r) * KD + col;
            char* lA = (char*)&sbuf[buf][0][0] + a * 4096 + wave * 1024;
            __builtin_amdgcn_global_load_lds(
                (const __attribute__((address_space(1))) void*)gA,
                (__attribute__((address_space(3))) void*)lA, 16, 0, 0);
            const unsigned short* gB = Fbf + (size_t)(j0s + r) * KD + col;
            char* lB = (char*)&sbuf[buf][1][0] + a * 4096 + wave * 1024;
            __builtin_amdgcn_global_load_lds(
                (const __attribute__((address_space(1))) void*)gB,
                (__attribute__((address_space(3))) void*)lB, 16, 0, 0);
        }
    };

    // persistent accumulators across the block's 8 j-tiles
    f32x4 acc_cs[4][2];
    float psum[4] = {0.f, 0.f, 0.f, 0.f};
    #pragma unroll
    for (int m = 0; m < 4; m++)
        #pragma unroll
        for (int cb = 0; cb < 2; cb++)
            acc_cs[m][cb] = (f32x4){0.f, 0.f, 0.f, 0.f};

    const int jt_beg = jc * JTPC, jt_end = (jc + 1) * JTPC;
    if (t < 128) slab[0][t] = labels[jt_beg * 128 + t];
    STAGE(0, jt_beg * 128, 0);   // prologue: first tile's k=0

    #pragma unroll 1
    for (int jt = jt_beg; jt < jt_end; ++jt) {
        const int j0 = jt * 128;
        const int cur = jt & 1;

        __syncthreads();   // drains prefetch (vm+lgkm); slab[cur] visible; sE reads done

        f32x4 acc[4][4];
        #pragma unroll
        for (int m = 0; m < 4; m++)
            #pragma unroll
            for (int n = 0; n < 4; n++)
                acc[m][n] = (f32x4){0.f, 0.f, 0.f, 0.f};

        // ---- 2-phase pipelined K-loop: 4 steps of BK=64 ----
        #pragma unroll 1
        for (int ks = 0; ks < 4; ++ks) {
            if (ks < 3) STAGE((ks + 1) & 1, j0, ks + 1);
            const unsigned short* pA = &sbuf[ks & 1][0][0];
            const unsigned short* pB = &sbuf[ks & 1][1][0];
            short8 bf4[4][2];
            #pragma unroll
            for (int n = 0; n < 4; ++n) {
                int r = wc * 64 + n * 16 + l15;
                #pragma unroll
                for (int kk = 0; kk < 2; ++kk)
                    bf4[n][kk] = *(const short8*)&pB[r * 64 + (((kk * 4 + l4) ^ (r & 7)) * 8)];
            }
            __builtin_amdgcn_s_setprio(1);
            #pragma unroll
            for (int m = 0; m < 4; ++m) {
                int r = wr * 64 + m * 16 + l15;
                short8 a0 = *(const short8*)&pA[r * 64 + ((l4 ^ (r & 7)) * 8)];
                short8 a1 = *(const short8*)&pA[r * 64 + (((4 + l4) ^ (r & 7)) * 8)];
                #pragma unroll
                for (int n = 0; n < 4; ++n) {   // swapped operands: q indexes j
                    acc[m][n] = __builtin_amdgcn_mfma_f32_16x16x32_bf16(bf4[n][0], a0, acc[m][n], 0, 0, 0);
                    acc[m][n] = __builtin_amdgcn_mfma_f32_16x16x32_bf16(bf4[n][1], a1, acc[m][n], 0, 0, 0);
                }
            }
            __builtin_amdgcn_s_setprio(0);
            __syncthreads();   // drains next stage; swaps buffers
        }

        // ---- prefetch next tile's k=0 into buf0 (dead); flies under epilogue ----
        if (jt + 1 < jt_end) STAGE(0, (jt + 1) * 128, 0);
        // load next tile's labels (double-buffered slab)
        if (jt + 1 < jt_end && t < 128) slab[cur ^ 1][t] = labels[(jt + 1) * 128 + t];

        // ---- fused epilogue: psum + E=2^sim' + cvt_pk pack -> wave-private sE [64][64] bf16 ----
        char* sEw = (char*)&sbuf[1][0][0] + wave * 8192;   // buf1 dead after K-loop barrier

        int4 lj4[4];                                       // hoisted: this wave-lane's j labels
        #pragma unroll
        for (int n = 0; n < 4; n++)
            lj4[n] = *(const int4*)&slab[cur][wc * 64 + n * 16 + l4 * 4];

        if (j0 != i0) {
            #pragma unroll
            for (int m = 0; m < 4; m++) {
                const int row = m * 16 + l15;
                #pragma unroll
                for (int n = 0; n < 4; n++) {
                    const int* ljp = (const int*)&lj4[n];
                    float e[4];
                    #pragma unroll
                    for (int q = 0; q < 4; q++) {
                        float sp = acc[m][n][q];                    // log2-scaled sim
                        psum[m] += (ljp[q] == labi[m]) ? sp : 0.0f;
                        e[q] = fexp2(sp);
                    }
                    uint2 w; w.x = pk2bf(e[0], e[1]); w.y = pk2bf(e[2], e[3]);
                    const int bc = (n * 32 + l4 * 8) ^ ((row & 7) << 4);
                    *(uint2*)(sEw + row * 128 + bc) = w;
                }
            }
        } else {   // diagonal tile: exclude self
            #pragma unroll
            for (int m = 0; m < 4; m++) {
                const int row = m * 16 + l15;
                const int ig = i0 + wr * 64 + row;
                #pragma unroll
                for (int n = 0; n < 4; n++) {
                    const int jb = wc * 64 + n * 16 + l4 * 4;
                    const int* ljp = (const int*)&lj4[n];
                    float e[4];
                    #pragma unroll
                    for (int q = 0; q < 4; q++) {
                        const int jg = j0 + jb + q;
                        float sp = acc[m][n][q];
                        bool self = (ig == jg);
                        psum[m] += (!self && ljp[q] == labi[m]) ? sp : 0.0f;
                        e[q] = self ? 0.0f : fexp2(sp);
                    }
                    uint2 w; w.x = pk2bf(e[0], e[1]); w.y = pk2bf(e[2], e[3]);
                    const int bc = (n * 32 + l4 * 8) ^ ((row & 7) << 4);
                    *(uint2*)(sEw + row * 128 + bc) = w;
                }
            }
        }

        // one-hot B-fragments over this wave's 64 j-cols (2 K=32 slices)
        short8 hf[2][2];
        #pragma unroll
        for (int kk = 0; kk < 2; kk++) {
            const int jb = wc * 64 + kk * 32 + l4 * 8;
            int4 lv0 = *(const int4*)&slab[cur][jb];
            int4 lv1 = *(const int4*)&slab[cur][jb + 4];
            int lv[8] = {lv0.x, lv0.y, lv0.z, lv0.w, lv1.x, lv1.y, lv1.z, lv1.w};
            #pragma unroll
            for (int cb = 0; cb < 2; cb++) {
                short8 h;
                #pragma unroll
                for (int e = 0; e < 8; e++)
                    h[e] = (lv[e] == cb * 16 + l15) ? (short)0x3F80 : (short)0;
                hf[kk][cb] = h;
            }
        }

        // CS MFMA from sEw (accumulate into persistent acc_cs)
        #pragma unroll
        for (int kk = 0; kk < 2; kk++) {
            #pragma unroll
            for (int m = 0; m < 4; m++) {
                const int row = m * 16 + l15;
                const int bc = (kk * 64 + l4 * 16) ^ ((row & 7) << 4);
                short8 ef = *(const short8*)(sEw + row * 128 + bc);
                #pragma unroll
                for (int cb = 0; cb < 2; cb++)
                    acc_cs[m][cb] = __builtin_amdgcn_mfma_f32_16x16x32_bf16(
                        ef, hf[kk][cb], acc_cs[m][cb], 0, 0, 0);
            }
        }
        // no barrier here: loop-top __syncthreads() protects buffers before reuse
    }

    // ---- block end: cross-wave (wc) reduce of CS + psum, write partials ----
    __syncthreads();
    float* scr = (float*)&sbuf[0][0][0];   // [128][33] f32 over dead dbuf
    float pv[4];
    #pragma unroll
    for (int m = 0; m < 4; m++) {
        float v = psum[m];
        v += __shfl_xor(v, 16, 64);
        v += __shfl_xor(v, 32, 64);
        pv[m] = v;
    }
    if (wc == 1) {
        #pragma unroll
        for (int m = 0; m < 4; m++) {
            #pragma unroll
            for (int cb = 0; cb < 2; cb++)
                #pragma unroll
                for (int q = 0; q < 4; q++)
                    scr[(wr * 64 + m * 16 + l4 * 4 + q) * 33 + cb * 16 + l15] =
                        acc_cs[m][cb][q];
            if (l4 == 0) sps[wr * 64 + m * 16 + l15] = pv[m];
        }
    }
    __syncthreads();
    if (wc == 0) {
        const size_t slot = (size_t)itile * NCHUNK + jc;
        float* pc = pcls + slot * 128 * NCLS;
        #pragma unroll
        for (int m = 0; m < 4; m++) {
            #pragma unroll
            for (int cb = 0; cb < 2; cb++)
                #pragma unroll
                for (int q = 0; q < 4; q++) {
                    const int r = wr * 64 + m * 16 + l4 * 4 + q;
                    const int c = cb * 16 + l15;
                    pc[r * NCLS + c] = acc_cs[m][cb][q] + scr[r * 33 + c];
                }
            if (l4 == 0)
                ppos[slot * 128 + wr * 64 + m * 16 + l15] =
                    (pv[m] + sps[wr * 64 + m * 16 + l15]) * LN2;   // back to 1/T units
        }
    }
}

// ---------------- kernel 3: per-anchor loss + deterministic fused final reduction ----------------
// 256 blocks x 256 threads (8 lanes/anchor, 32 anchors/block). Block partial -> int atomicAdd
// (associative => deterministic); last block (ticket) computes the scalar output.
__global__ void reduce_kernel(const float* __restrict__ pcls, const float* __restrict__ ppos,
                              const int* __restrict__ counts, const int* __restrict__ labels,
                              int* __restrict__ acc_loss, int* __restrict__ acc_valid,
                              int* __restrict__ ticket, float* __restrict__ out) {
    __shared__ float ssum[256];
    __shared__ float scnt[256];
    int tid = blockIdx.x * blockDim.x + threadIdx.x;
    int i  = tid >> 3;
    int cq = tid & 7;
    int itile = i >> 7, ilocal = i & 127;

    f32x4 cs = (f32x4){0.f, 0.f, 0.f, 0.f};
    for (int ch = 0; ch < NCHUNK; ch++) {
        const float* p = pcls + ((size_t)(itile * NCHUNK + ch) * 128 + ilocal) * NCLS + cq * 4;
        f32x4 v = *(const f32x4*)p;
        cs = cs + v;
    }
    int labi = labels[i];
    float dpart = 0.0f;
    #pragma unroll
    for (int e = 0; e < 4; e++) {
        int c = cq * 4 + e;
        int cnt = counts[c] - (c == labi ? 1 : 0);
        if (cnt > 0) dpart += cs[e] / (float)cnt;
    }
    #pragma unroll
    for (int off = 1; off < 8; off <<= 1) dpart += __shfl_xor(dpart, off, 64);

    float li = 0.0f, vf = 0.0f;
    if (cq == 0) {
        float psum = 0.0f;
        for (int ch = 0; ch < NCHUNK; ch++)
            psum += ppos[(size_t)(itile * NCHUNK + ch) * 128 + ilocal];
        int P = counts[labi] - 1;
        if (P > 0) {
            li = logf(fmaxf(dpart, 1e-30f)) - psum / (float)P;
            vf = 1.0f;
        }
    }
    int t = threadIdx.x;
    ssum[t] = li; scnt[t] = vf;
    __syncthreads();
    #pragma unroll
    for (int off = 128; off > 0; off >>= 1) {
        if (t < off) { ssum[t] += ssum[t + off]; scnt[t] += scnt[t + off]; }
        __syncthreads();
    }
    if (t == 0) {
        atomicAdd(acc_loss, __float2int_rn(ssum[0] * ACC_SCALE));
        atomicAdd(acc_valid, (int)(scnt[0] + 0.5f));
        __threadfence();
        int tk = atomicAdd(ticket, 1);
        if (tk == 255) {   // last block: all partials visible (fence-before-ticket)
            int ls = atomicAdd(acc_loss, 0);
            int nv = atomicAdd(acc_valid, 0);
            out[0] = (nv > 0) ? ((float)ls / ACC_SCALE) / (float)nv : 0.0f;
        }
    }
}

// ---------------- launch ----------------
extern "C" void kernel_launch(void* const* d_in, const int* in_sizes, int n_in,
                              void* d_out, int out_size, void* d_ws, size_t ws_size,
                              hipStream_t stream) {
    const float* feat   = (const float*)d_in[0];
    const int*   labels = (const int*)d_in[1];
    float*       out    = (float*)d_out;

    char* ws = (char*)d_ws;
    size_t off = 0;
    auto alloc = [&](size_t bytes) -> void* {
        void* p = ws + off;
        off = (off + bytes + 255) & ~(size_t)255;
        return p;
    };

    // zero-initialized control block (counts + accumulators + ticket), one memset
    int* ctrl = (int*)alloc(256);              // [0..31]=counts, [32]=acc_loss, [33]=acc_valid, [34]=ticket
    int* counts    = ctrl;
    int* acc_loss  = ctrl + 32;
    int* acc_valid = ctrl + 33;
    int* ticket    = ctrl + 34;

    unsigned short* Fbf = (unsigned short*)alloc((size_t)B_SZ * KD * 2);      // 4.2MB
    float* ppos   = (float*)alloc((size_t)512 * 128 * 4);                     // 256KB
    float* pcls   = (float*)alloc((size_t)512 * 128 * NCLS * 4);              // 8.4MB

    hipMemsetAsync(ctrl, 0, 256, stream);
    prep_kernel<<<B_SZ / 4, 256, 0, stream>>>(feat, Fbf, labels, counts);
    sim_kernel<<<512, 256, 0, stream>>>(Fbf, labels, pcls, ppos);
    reduce_kernel<<<B_SZ * 8 / 256, 256, 0, stream>>>(pcls, ppos, counts, labels,
                                                      acc_loss, acc_valid, ticket, out);
}

// Round 23
// 80.181 us; speedup vs baseline: 1.3841x; 1.0020x over previous
//
#include <hip/hip_runtime.h>
#include <hip/hip_bf16.h>
#include <math.h>
#include <string.h>

#define B_SZ  8192
#define KD    256
#define NCLS  32
#define NCHUNK 8          // j-chunks per i-tile row; grid = 64*NCHUNK = 512 blocks
#define JTPC   8          // 128-wide j-tiles per block
#define SCALE_LOG2 3.79828243f   // sqrt(10 * log2(e)): rows scaled so sim' = (sim/T)*log2(e)
#define LN2 0.69314718056f
#define ACC_SCALE 2048.0f        // fixed-point scale for deterministic loss accumulation

typedef __attribute__((ext_vector_type(8))) short short8;
typedef __attribute__((ext_vector_type(4))) float f32x4;

static __device__ __forceinline__ unsigned pk2bf(float a, float b) {
    __hip_bfloat162 h = __float22bfloat162_rn(make_float2(a, b));   // v_cvt_pk_bf16_f32
    unsigned u; __builtin_memcpy(&u, &h, 4); return u;
}
static __device__ __forceinline__ float fexp2(float x) {   // raw v_exp_f32: D = 2^S0
    float r;
    asm("v_exp_f32 %0, %1" : "=v"(r) : "v"(x));
    return r;
}

// ---------------- kernel 1: normalize+scale rows -> bf16 (log2e folded) + fused label counts ----------------
__global__ void prep_kernel(const float* __restrict__ feat, unsigned short* __restrict__ Fbf,
                            const int* __restrict__ labels, int* __restrict__ counts) {
    __shared__ int sc[NCLS];
    const int blk = blockIdx.x;
    const int t   = threadIdx.x;
    const bool docnt = (blk < 32);   // 32 blocks x 256 labels = 8192
    if (docnt) {
        if (t < NCLS) sc[t] = 0;
        __syncthreads();
        atomicAdd(&sc[labels[blk * 256 + t]], 1);
    }

    int row  = blk * 4 + (t >> 6);
    int lane = t & 63;
    const float4 v = ((const float4*)(feat + (size_t)row * KD))[lane];
    float s = v.x * v.x + v.y * v.y + v.z * v.z + v.w * v.w;
    #pragma unroll
    for (int off = 1; off < 64; off <<= 1) s += __shfl_xor(s, off, 64);
    float rn = rsqrtf(s) * SCALE_LOG2;
    uint2 w;
    w.x = pk2bf(v.x * rn, v.y * rn);
    w.y = pk2bf(v.z * rn, v.w * rn);
    ((uint2*)(Fbf + (size_t)row * KD))[lane] = w;

    if (docnt) {
        __syncthreads();
        if (t < NCLS) atomicAdd(&counts[t], sc[t]);
    }
}

// ---------------- kernel 2: 128x128 bf16 sim GEMM (BK=64) + fused epilogue + MFMA class reduce ----------------
// 512 blocks (2/CU), 256 threads = 4 waves 2x2; wave owns 64x64 of C.  [verified R17/R20 form]
__global__ __launch_bounds__(256, 2) void sim_kernel(
    const unsigned short* __restrict__ Fbf, const int* __restrict__ labels,
    float* __restrict__ pcls, float* __restrict__ ppos)
{
    __shared__ __align__(16) unsigned short sbuf[2][2][128 * 64];  // 64KB: [buf][A/B], BK=64
    __shared__ int   slab[2][128];
    __shared__ float sps[128];

    const int bid = blockIdx.x;
    const int swz = (bid & 7) * 64 + (bid >> 3);   // bijective XCD swizzle (512 % 8 == 0)
    const int itile = swz >> 3;                    // swz / NCHUNK
    const int jc    = swz & 7;                     // swz % NCHUNK
    const int i0    = itile * 128;

    const int t    = threadIdx.x;
    const int wave = t >> 6;
    const int lane = t & 63;
    const int wr   = wave >> 1;      // 0..1 -> 64-row half
    const int wc   = wave & 1;       // 0..1 -> 64-col half
    const int l15  = lane & 15;
    const int l4   = lane >> 4;

    int labi[4];
    #pragma unroll
    for (int m = 0; m < 4; m++) labi[m] = labels[i0 + wr * 64 + m * 16 + l15];

    const int rT = t >> 3;    // row-within-32 staged per quarter
    const int s8 = t & 7;     // physical 16B slot

    auto STAGE = [&](int buf, int j0s, int ks) {
        const int kc = ks * 64;
        #pragma unroll
        for (int a = 0; a < 4; ++a) {
            int r   = a * 32 + rT;
            int sl  = s8 ^ (r & 7);          // logical k-slot (involution)
            int col = kc + sl * 8;
            const unsigned short* gA = Fbf + (size_t)(i0 + r) * KD + col;
            char* lA = (char*)&sbuf[buf][0][0] + a * 4096 + wave * 1024;
            __builtin_amdgcn_global_load_lds(
                (const __attribute__((address_space(1))) void*)gA,
                (__attribute__((address_space(3))) void*)lA, 16, 0, 0);
            const unsigned short* gB = Fbf + (size_t)(j0s + r) * KD + col;
            char* lB = (char*)&sbuf[buf][1][0] + a * 4096 + wave * 1024;
            __builtin_amdgcn_global_load_lds(
                (const __attribute__((address_space(1))) void*)gB,
                (__attribute__((address_space(3))) void*)lB, 16, 0, 0);
        }
    };

    // persistent accumulators across the block's 8 j-tiles
    f32x4 acc_cs[4][2];
    float psum[4] = {0.f, 0.f, 0.f, 0.f};
    #pragma unroll
    for (int m = 0; m < 4; m++)
        #pragma unroll
        for (int cb = 0; cb < 2; cb++)
            acc_cs[m][cb] = (f32x4){0.f, 0.f, 0.f, 0.f};

    const int jt_beg = jc * JTPC, jt_end = (jc + 1) * JTPC;
    if (t < 128) slab[0][t] = labels[jt_beg * 128 + t];
    STAGE(0, jt_beg * 128, 0);   // prologue: first tile's k=0

    #pragma unroll 1
    for (int jt = jt_beg; jt < jt_end; ++jt) {
        const int j0 = jt * 128;
        const int cur = jt & 1;

        __syncthreads();   // drains prefetch (vm+lgkm); slab[cur] visible; sE reads done

        f32x4 acc[4][4];
        #pragma unroll
        for (int m = 0; m < 4; m++)
            #pragma unroll
            for (int n = 0; n < 4; n++)
                acc[m][n] = (f32x4){0.f, 0.f, 0.f, 0.f};

        // ---- 2-phase pipelined K-loop: 4 steps of BK=64 ----
        #pragma unroll 1
        for (int ks = 0; ks < 4; ++ks) {
            if (ks < 3) STAGE((ks + 1) & 1, j0, ks + 1);
            const unsigned short* pA = &sbuf[ks & 1][0][0];
            const unsigned short* pB = &sbuf[ks & 1][1][0];
            short8 bf4[4][2];
            #pragma unroll
            for (int n = 0; n < 4; ++n) {
                int r = wc * 64 + n * 16 + l15;
                #pragma unroll
                for (int kk = 0; kk < 2; ++kk)
                    bf4[n][kk] = *(const short8*)&pB[r * 64 + (((kk * 4 + l4) ^ (r & 7)) * 8)];
            }
            __builtin_amdgcn_s_setprio(1);
            #pragma unroll
            for (int m = 0; m < 4; ++m) {
                int r = wr * 64 + m * 16 + l15;
                short8 a0 = *(const short8*)&pA[r * 64 + ((l4 ^ (r & 7)) * 8)];
                short8 a1 = *(const short8*)&pA[r * 64 + (((4 + l4) ^ (r & 7)) * 8)];
                #pragma unroll
                for (int n = 0; n < 4; ++n) {   // swapped operands: q indexes j
                    acc[m][n] = __builtin_amdgcn_mfma_f32_16x16x32_bf16(bf4[n][0], a0, acc[m][n], 0, 0, 0);
                    acc[m][n] = __builtin_amdgcn_mfma_f32_16x16x32_bf16(bf4[n][1], a1, acc[m][n], 0, 0, 0);
                }
            }
            __builtin_amdgcn_s_setprio(0);
            __syncthreads();   // drains next stage; swaps buffers
        }

        // ---- prefetch next tile's k=0 into buf0 (dead); flies under epilogue ----
        if (jt + 1 < jt_end) STAGE(0, (jt + 1) * 128, 0);
        // load next tile's labels (double-buffered slab)
        if (jt + 1 < jt_end && t < 128) slab[cur ^ 1][t] = labels[(jt + 1) * 128 + t];

        // ---- fused epilogue: psum + E=2^sim' + cvt_pk pack -> wave-private sE [64][64] bf16 ----
        char* sEw = (char*)&sbuf[1][0][0] + wave * 8192;   // buf1 dead after K-loop barrier

        int4 lj4[4];                                       // hoisted: this wave-lane's j labels
        #pragma unroll
        for (int n = 0; n < 4; n++)
            lj4[n] = *(const int4*)&slab[cur][wc * 64 + n * 16 + l4 * 4];

        if (j0 != i0) {
            #pragma unroll
            for (int m = 0; m < 4; m++) {
                const int row = m * 16 + l15;
                #pragma unroll
                for (int n = 0; n < 4; n++) {
                    const int* ljp = (const int*)&lj4[n];
                    float e[4];
                    #pragma unroll
                    for (int q = 0; q < 4; q++) {
                        float sp = acc[m][n][q];                    // log2-scaled sim
                        psum[m] += (ljp[q] == labi[m]) ? sp : 0.0f;
                        e[q] = fexp2(sp);
                    }
                    uint2 w; w.x = pk2bf(e[0], e[1]); w.y = pk2bf(e[2], e[3]);
                    const int bc = (n * 32 + l4 * 8) ^ ((row & 7) << 4);
                    *(uint2*)(sEw + row * 128 + bc) = w;
                }
            }
        } else {   // diagonal tile: exclude self
            #pragma unroll
            for (int m = 0; m < 4; m++) {
                const int row = m * 16 + l15;
                const int ig = i0 + wr * 64 + row;
                #pragma unroll
                for (int n = 0; n < 4; n++) {
                    const int jb = wc * 64 + n * 16 + l4 * 4;
                    const int* ljp = (const int*)&lj4[n];
                    float e[4];
                    #pragma unroll
                    for (int q = 0; q < 4; q++) {
                        const int jg = j0 + jb + q;
                        float sp = acc[m][n][q];
                        bool self = (ig == jg);
                        psum[m] += (!self && ljp[q] == labi[m]) ? sp : 0.0f;
                        e[q] = self ? 0.0f : fexp2(sp);
                    }
                    uint2 w; w.x = pk2bf(e[0], e[1]); w.y = pk2bf(e[2], e[3]);
                    const int bc = (n * 32 + l4 * 8) ^ ((row & 7) << 4);
                    *(uint2*)(sEw + row * 128 + bc) = w;
                }
            }
        }

        // one-hot B-fragments over this wave's 64 j-cols (2 K=32 slices)
        short8 hf[2][2];
        #pragma unroll
        for (int kk = 0; kk < 2; kk++) {
            const int jb = wc * 64 + kk * 32 + l4 * 8;
            int4 lv0 = *(const int4*)&slab[cur][jb];
            int4 lv1 = *(const int4*)&slab[cur][jb + 4];
            int lv[8] = {lv0.x, lv0.y, lv0.z, lv0.w, lv1.x, lv1.y, lv1.z, lv1.w};
            #pragma unroll
            for (int cb = 0; cb < 2; cb++) {
                short8 h;
                #pragma unroll
                for (int e = 0; e < 8; e++)
                    h[e] = (lv[e] == cb * 16 + l15) ? (short)0x3F80 : (short)0;
                hf[kk][cb] = h;
            }
        }

        // CS MFMA from sEw (accumulate into persistent acc_cs)
        #pragma unroll
        for (int kk = 0; kk < 2; kk++) {
            #pragma unroll
            for (int m = 0; m < 4; m++) {
                const int row = m * 16 + l15;
                const int bc = (kk * 64 + l4 * 16) ^ ((row & 7) << 4);
                short8 ef = *(const short8*)(sEw + row * 128 + bc);
                #pragma unroll
                for (int cb = 0; cb < 2; cb++)
                    acc_cs[m][cb] = __builtin_amdgcn_mfma_f32_16x16x32_bf16(
                        ef, hf[kk][cb], acc_cs[m][cb], 0, 0, 0);
            }
        }
        // no barrier here: loop-top __syncthreads() protects buffers before reuse
    }

    // ---- block end: cross-wave (wc) reduce of CS + psum, write partials ----
    __syncthreads();
    float* scr = (float*)&sbuf[0][0][0];   // [128][33] f32 over dead dbuf
    float pv[4];
    #pragma unroll
    for (int m = 0; m < 4; m++) {
        float v = psum[m];
        v += __shfl_xor(v, 16, 64);
        v += __shfl_xor(v, 32, 64);
        pv[m] = v;
    }
    if (wc == 1) {
        #pragma unroll
        for (int m = 0; m < 4; m++) {
            #pragma unroll
            for (int cb = 0; cb < 2; cb++)
                #pragma unroll
                for (int q = 0; q < 4; q++)
                    scr[(wr * 64 + m * 16 + l4 * 4 + q) * 33 + cb * 16 + l15] =
                        acc_cs[m][cb][q];
            if (l4 == 0) sps[wr * 64 + m * 16 + l15] = pv[m];
        }
    }
    __syncthreads();
    if (wc == 0) {
        const size_t slot = (size_t)itile * NCHUNK + jc;
        float* pc = pcls + slot * 128 * NCLS;
        #pragma unroll
        for (int m = 0; m < 4; m++) {
            #pragma unroll
            for (int cb = 0; cb < 2; cb++)
                #pragma unroll
                for (int q = 0; q < 4; q++) {
                    const int r = wr * 64 + m * 16 + l4 * 4 + q;
                    const int c = cb * 16 + l15;
                    pc[r * NCLS + c] = acc_cs[m][cb][q] + scr[r * 33 + c];
                }
            if (l4 == 0)
                ppos[slot * 128 + wr * 64 + m * 16 + l15] =
                    (pv[m] + sps[wr * 64 + m * 16 + l15]) * LN2;   // back to 1/T units
        }
    }
}

// ---------------- kernel 3: per-anchor loss + deterministic fused final reduction ----------------
// 256 blocks x 256 threads (8 lanes/anchor, 32 anchors/block). Block partial -> int atomicAdd
// (associative => deterministic); last block (ticket) computes the scalar output.
__global__ void reduce_kernel(const float* __restrict__ pcls, const float* __restrict__ ppos,
                              const int* __restrict__ counts, const int* __restrict__ labels,
                              int* __restrict__ acc_loss, int* __restrict__ acc_valid,
                              int* __restrict__ ticket, float* __restrict__ out) {
    __shared__ float ssum[256];
    __shared__ float scnt[256];
    int tid = blockIdx.x * blockDim.x + threadIdx.x;
    int i  = tid >> 3;
    int cq = tid & 7;
    int itile = i >> 7, ilocal = i & 127;

    f32x4 cs = (f32x4){0.f, 0.f, 0.f, 0.f};
    for (int ch = 0; ch < NCHUNK; ch++) {
        const float* p = pcls + ((size_t)(itile * NCHUNK + ch) * 128 + ilocal) * NCLS + cq * 4;
        f32x4 v = *(const f32x4*)p;
        cs = cs + v;
    }
    int labi = labels[i];
    float dpart = 0.0f;
    #pragma unroll
    for (int e = 0; e < 4; e++) {
        int c = cq * 4 + e;
        int cnt = counts[c] - (c == labi ? 1 : 0);
        if (cnt > 0) dpart += cs[e] / (float)cnt;
    }
    #pragma unroll
    for (int off = 1; off < 8; off <<= 1) dpart += __shfl_xor(dpart, off, 64);

    float li = 0.0f, vf = 0.0f;
    if (cq == 0) {
        float psum = 0.0f;
        for (int ch = 0; ch < NCHUNK; ch++)
            psum += ppos[(size_t)(itile * NCHUNK + ch) * 128 + ilocal];
        int P = counts[labi] - 1;
        if (P > 0) {
            li = logf(fmaxf(dpart, 1e-30f)) - psum / (float)P;
            vf = 1.0f;
        }
    }
    int t = threadIdx.x;
    ssum[t] = li; scnt[t] = vf;
    __syncthreads();
    #pragma unroll
    for (int off = 128; off > 0; off >>= 1) {
        if (t < off) { ssum[t] += ssum[t + off]; scnt[t] += scnt[t + off]; }
        __syncthreads();
    }
    if (t == 0) {
        atomicAdd(acc_loss, __float2int_rn(ssum[0] * ACC_SCALE));
        atomicAdd(acc_valid, (int)(scnt[0] + 0.5f));
        __threadfence();
        int tk = atomicAdd(ticket, 1);
        if (tk == 255) {   // last block: all partials visible (fence-before-ticket)
            int ls = atomicAdd(acc_loss, 0);
            int nv = atomicAdd(acc_valid, 0);
            out[0] = (nv > 0) ? ((float)ls / ACC_SCALE) / (float)nv : 0.0f;
        }
    }
}

// ---------------- launch ----------------
extern "C" void kernel_launch(void* const* d_in, const int* in_sizes, int n_in,
                              void* d_out, int out_size, void* d_ws, size_t ws_size,
                              hipStream_t stream) {
    const float* feat   = (const float*)d_in[0];
    const int*   labels = (const int*)d_in[1];
    float*       out    = (float*)d_out;

    char* ws = (char*)d_ws;
    size_t off = 0;
    auto alloc = [&](size_t bytes) -> void* {
        void* p = ws + off;
        off = (off + bytes + 255) & ~(size_t)255;
        return p;
    };

    // zero-initialized control block (counts + accumulators + ticket), one memset
    int* ctrl = (int*)alloc(256);              // [0..31]=counts, [32]=acc_loss, [33]=acc_valid, [34]=ticket
    int* counts    = ctrl;
    int* acc_loss  = ctrl + 32;
    int* acc_valid = ctrl + 33;
    int* ticket    = ctrl + 34;

    unsigned short* Fbf = (unsigned short*)alloc((size_t)B_SZ * KD * 2);      // 4.2MB
    float* ppos   = (float*)alloc((size_t)512 * 128 * 4);                     // 256KB
    float* pcls   = (float*)alloc((size_t)512 * 128 * NCLS * 4);              // 8.4MB

    hipMemsetAsync(ctrl, 0, 256, stream);
    prep_kernel<<<B_SZ / 4, 256, 0, stream>>>(feat, Fbf, labels, counts);
    sim_kernel<<<512, 256, 0, stream>>>(Fbf, labels, pcls, ppos);
    reduce_kernel<<<B_SZ * 8 / 256, 256, 0, stream>>>(pcls, ppos, counts, labels,
                                                      acc_loss, acc_valid, ticket, out);
}